// Round 1
// baseline (826.522 us; speedup 1.0000x reference)
//
#include <hip/hip_runtime.h>

#define H 4
#define D 64
#define C 256   // H*D = out cols of W_fc
#define IN_F 256
#define EF 64
#define NEG 0.2f
#define NT 16   // nodes per block in projection

// ---------------- K0: per-etype attention term ee[t][h] ----------------
__global__ void k_etype(const float* __restrict__ edge_emb, const float* __restrict__ W_e,
                        const float* __restrict__ attn_e, float* __restrict__ ee) {
    int t = blockIdx.x;          // etype 0..7
    int c = threadIdx.x;         // h*64+f
    float acc = 0.f;
    #pragma unroll 8
    for (int k = 0; k < EF; ++k)
        acc += edge_emb[t * EF + k] * W_e[k * C + c];
    acc *= attn_e[c];
    #pragma unroll
    for (int s = 32; s > 0; s >>= 1) acc += __shfl_down(acc, s, 64);
    if ((threadIdx.x & 63) == 0) ee[t * H + (threadIdx.x >> 6)] = acc;
}

// ---------------- K1: ft = feat @ W_fc, fused el/er ----------------
__global__ void k_proj(const float* __restrict__ feat, const float* __restrict__ W_fc,
                       const float* __restrict__ attn_l, const float* __restrict__ attn_r,
                       float* __restrict__ ft, float* __restrict__ el, float* __restrict__ er,
                       int N) {
    int c  = threadIdx.x;            // output column 0..255
    int n0 = blockIdx.x * NT;
    float acc[NT];
    #pragma unroll
    for (int i = 0; i < NT; ++i) acc[i] = 0.f;

    for (int k0 = 0; k0 < IN_F; k0 += 4) {
        float4 fv[NT];
        #pragma unroll
        for (int i = 0; i < NT; ++i) {
            int n = n0 + i; if (n >= N) n = N - 1;     // safe clamp (N%NT==0 normally)
            fv[i] = *(const float4*)(feat + (size_t)n * IN_F + k0);  // block-uniform -> s_load
        }
        #pragma unroll
        for (int kk = 0; kk < 4; ++kk) {
            float w = W_fc[(size_t)(k0 + kk) * C + c];  // coalesced, L2-hot
            #pragma unroll
            for (int i = 0; i < NT; ++i)
                acc[i] = fmaf((&fv[i].x)[kk], w, acc[i]);
        }
    }

    float al = attn_l[c], ar = attn_r[c];
    int h = threadIdx.x >> 6;        // wave == head
    #pragma unroll
    for (int i = 0; i < NT; ++i) {
        int n = n0 + i;
        float vl = acc[i] * al, vr = acc[i] * ar;
        #pragma unroll
        for (int s = 32; s > 0; s >>= 1) {
            vl += __shfl_down(vl, s, 64);
            vr += __shfl_down(vr, s, 64);
        }
        if (n < N) {
            ft[(size_t)n * C + c] = acc[i];
            if ((threadIdx.x & 63) == 0) { el[n * H + h] = vl; er[n * H + h] = vr; }
        }
    }
}

// ---------------- K2: in-degree count ----------------
__global__ void k_deg(const int* __restrict__ dst, unsigned* __restrict__ deg, int E) {
    int e = blockIdx.x * blockDim.x + threadIdx.x;
    if (e < E) atomicAdd(&deg[dst[e]], 1u);
}

// ---------------- K3: exclusive prefix sum (single block) ----------------
__global__ void k_scan(const unsigned* __restrict__ deg, unsigned* __restrict__ off, int n) {
    __shared__ unsigned tmp[1024];
    __shared__ unsigned carry;
    int tid = threadIdx.x;
    if (tid == 0) carry = 0;
    __syncthreads();
    for (int base = 0; base < n; base += 1024) {
        unsigned v = (base + tid < n) ? deg[base + tid] : 0u;
        tmp[tid] = v; __syncthreads();
        for (int s = 1; s < 1024; s <<= 1) {
            unsigned add = (tid >= s) ? tmp[tid - s] : 0u;
            __syncthreads();
            tmp[tid] += add;
            __syncthreads();
        }
        unsigned exc = tmp[tid] - v;
        unsigned cr = carry;
        if (base + tid < n) off[base + tid] = cr + exc;
        __syncthreads();
        if (tid == 1023) carry = cr + tmp[1023];
        __syncthreads();
    }
    if (tid == 0) off[n] = carry;
}

// ---------------- K4: scatter edge ids into CSR ----------------
__global__ void k_scatter(const int* __restrict__ dst, const unsigned* __restrict__ off,
                          unsigned* __restrict__ cursor, unsigned* __restrict__ sorted, int E) {
    int e = blockIdx.x * blockDim.x + threadIdx.x;
    if (e < E) {
        int d = dst[e];
        unsigned p = atomicAdd(&cursor[d], 1u);
        sorted[off[d] + p] = (unsigned)e;
    }
}

// ---------------- K5: per-edge logits -> exp ----------------
__global__ void k_logit(const int* __restrict__ efeat, const int* __restrict__ src,
                        const int* __restrict__ dst,
                        const float* __restrict__ el, const float* __restrict__ er,
                        const float* __restrict__ ee, float* __restrict__ ex, int E) {
    int g = blockIdx.x * blockDim.x + threadIdx.x;
    if (g >= E * H) return;
    int e = g >> 2, h = g & 3;
    float v = el[src[e] * H + h] + er[dst[e] * H + h] + ee[efeat[e] * H + h];
    v = v > 0.f ? v : NEG * v;
    ex[g] = expf(v);   // logits are O(+-8); shift-invariant softmax needs no segment max
}

// ---------------- K6: wave-per-node softmax denom + gather-aggregate ----------------
__global__ void k_agg(const unsigned* __restrict__ off, const unsigned* __restrict__ sorted,
                      const int* __restrict__ src, const float* __restrict__ ex,
                      const float4* __restrict__ ft4, float4* __restrict__ out_rst4,
                      float* __restrict__ out_a, int N) {
    int wave = (int)((blockIdx.x * (size_t)blockDim.x + threadIdx.x) >> 6);
    if (wave >= N) return;
    int lane = threadIdx.x & 63;
    int h = lane >> 4;                      // 16 lanes per head
    unsigned beg = off[wave], end = off[wave + 1];

    float s = 0.f;
    for (unsigned j = beg; j < end; ++j) {
        unsigned eid = sorted[j];
        s += ex[eid * H + h];
    }
    float s0 = __shfl(s, 0, 64), s1 = __shfl(s, 16, 64),
          s2 = __shfl(s, 32, 64), s3 = __shfl(s, 48, 64);
    float inv  = (end > beg) ? 1.f / s : 0.f;
    float invw = 1.f;
    if (lane < 4) {
        float sw = (lane == 0) ? s0 : (lane == 1) ? s1 : (lane == 2) ? s2 : s3;
        invw = 1.f / sw;
    }

    float4 acc = make_float4(0.f, 0.f, 0.f, 0.f);
    for (unsigned j = beg; j < end; ++j) {
        unsigned eid = sorted[j];
        int sn = src[eid];
        float a = ex[eid * H + h] * inv;
        float4 f = ft4[(size_t)sn * 64 + lane];
        acc.x = fmaf(f.x, a, acc.x);
        acc.y = fmaf(f.y, a, acc.y);
        acc.z = fmaf(f.z, a, acc.z);
        acc.w = fmaf(f.w, a, acc.w);
        if (lane < 4) out_a[eid * H + lane] = ex[eid * H + lane] * invw;
    }
    out_rst4[(size_t)wave * 64 + lane] = acc;
}

extern "C" void kernel_launch(void* const* d_in, const int* in_sizes, int n_in,
                              void* d_out, int out_size, void* d_ws, size_t ws_size,
                              hipStream_t stream) {
    const float* feat     = (const float*)d_in[0];
    const int*   e_feat   = (const int*)d_in[1];
    const int*   src      = (const int*)d_in[2];
    const int*   dst      = (const int*)d_in[3];
    const float* W_fc     = (const float*)d_in[4];
    const float* W_e      = (const float*)d_in[5];
    const float* edge_emb = (const float*)d_in[6];
    const float* attn_l   = (const float*)d_in[7];
    const float* attn_r   = (const float*)d_in[8];
    const float* attn_e   = (const float*)d_in[9];

    int N = in_sizes[0] / IN_F;
    int E = in_sizes[1];

    float* out_rst = (float*)d_out;
    float* out_a   = out_rst + (size_t)N * C;

    // workspace layout (f32 units), 16B-aligned sections
    float* ft = (float*)d_ws;
    float* el = ft + (size_t)N * C;
    float* er = el + (size_t)N * H;
    float* ee = er + (size_t)N * H;
    float* ex = ee + 64;                       // 32 used, pad to 64 for alignment
    unsigned* deg    = (unsigned*)(ex + (size_t)E * H);
    unsigned* off    = deg + N;
    unsigned* cursor = off + (N + 1);
    unsigned* sorted = cursor + N;

    hipMemsetAsync(deg, 0, (size_t)N * sizeof(unsigned), stream);
    hipMemsetAsync(cursor, 0, (size_t)N * sizeof(unsigned), stream);

    k_etype  <<<8, 256, 0, stream>>>(edge_emb, W_e, attn_e, ee);
    k_proj   <<<(N + NT - 1) / NT, 256, 0, stream>>>(feat, W_fc, attn_l, attn_r, ft, el, er, N);
    k_deg    <<<(E + 255) / 256, 256, 0, stream>>>(dst, deg, E);
    k_scan   <<<1, 1024, 0, stream>>>(deg, off, N);
    k_scatter<<<(E + 255) / 256, 256, 0, stream>>>(dst, off, cursor, sorted, E);
    k_logit  <<<(E * H + 255) / 256, 256, 0, stream>>>(e_feat, src, dst, el, er, ee, ex, E);
    k_agg    <<<((size_t)N * 64 + 255) / 256, 256, 0, stream>>>(off, sorted, src, ex,
                                                                (const float4*)ft,
                                                                (float4*)out_rst, out_a, N);
}

// Round 2
// 551.139 us; speedup vs baseline: 1.4997x; 1.4997x over previous
//
#include <hip/hip_runtime.h>

#define H 4
#define D 64
#define C 256   // H*D
#define IN_F 256
#define EF 64
#define NEG 0.2f

typedef unsigned short ushort_t;
typedef __attribute__((ext_vector_type(8))) short bf16x8;
typedef __attribute__((ext_vector_type(4))) float f32x4;

__device__ __forceinline__ ushort_t f2bf(float x) {
    unsigned u = __float_as_uint(x);
    unsigned r = u + 0x7FFFu + ((u >> 16) & 1u);   // RNE
    return (ushort_t)(r >> 16);
}
__device__ __forceinline__ float bf2f(ushort_t u) {
    return __uint_as_float(((unsigned)u) << 16);
}

// ---------------- K0: per-etype attention term ee[t][h] ----------------
__global__ void k_etype(const float* __restrict__ edge_emb, const float* __restrict__ W_e,
                        const float* __restrict__ attn_e, float* __restrict__ ee) {
    int t = blockIdx.x;          // etype 0..7
    int c = threadIdx.x;         // h*64+f
    float acc = 0.f;
    #pragma unroll 8
    for (int k = 0; k < EF; ++k)
        acc += edge_emb[t * EF + k] * W_e[k * C + c];
    acc *= attn_e[c];
    #pragma unroll
    for (int s = 32; s > 0; s >>= 1) acc += __shfl_down(acc, s, 64);
    if ((threadIdx.x & 63) == 0) ee[t * H + (threadIdx.x >> 6)] = acc;
}

// ---------------- K1a: feat f32 -> bf16 (padded rows zeroed) ----------------
__global__ void k_featbf(const float* __restrict__ feat, ushort_t* __restrict__ out,
                         int N, int Mpad) {
    int g = blockIdx.x * 256 + threadIdx.x;          // one per 8 elems
    int total = Mpad * 32;                            // 256/8 per row
    if (g >= total) return;
    int row = g >> 5;
    int c8 = (g & 31) * 8;
    ushort_t v[8];
    if (row < N) {
        float4 a = *(const float4*)(feat + (size_t)row * 256 + c8);
        float4 b = *(const float4*)(feat + (size_t)row * 256 + c8 + 4);
        v[0]=f2bf(a.x); v[1]=f2bf(a.y); v[2]=f2bf(a.z); v[3]=f2bf(a.w);
        v[4]=f2bf(b.x); v[5]=f2bf(b.y); v[6]=f2bf(b.z); v[7]=f2bf(b.w);
    } else {
        #pragma unroll
        for (int i = 0; i < 8; ++i) v[i] = 0;
    }
    *(uint4*)(out + (size_t)row * 256 + c8) = *(uint4*)v;
}

// ---------------- K1b: W_fc -> W^T bf16  (WT[n][k]) ----------------
__global__ void k_wt(const float* __restrict__ W, ushort_t* __restrict__ WT) {
    int n = blockIdx.x, k = threadIdx.x;
    WT[n * 256 + k] = f2bf(W[(size_t)k * 256 + n]);
}

// ---------------- K1c: GEMM ft = feat @ W_fc (bf16 MFMA), fused el/er ----------------
#define BM 128
#define BN 128
#define BK 64
__launch_bounds__(256, 2)
__global__ void k_gemm(const ushort_t* __restrict__ Abf, const ushort_t* __restrict__ Bbf,
                       const float* __restrict__ attn_l, const float* __restrict__ attn_r,
                       ushort_t* __restrict__ ftbf, float* __restrict__ el, float* __restrict__ er,
                       int N) {
    __shared__ ushort_t As[BM * BK];   // XOR-swizzled: chunk (row, kg^(row&7))
    __shared__ ushort_t Bs[BN * BK];
    int t = threadIdx.x;
    int l = t & 63, w = t >> 6;
    int wr = w >> 1, wc = w & 1;       // 2x2 waves, 64x64 each
    int m0 = blockIdx.x * BM;
    int n0 = blockIdx.y * BN;

    f32x4 zero = {0.f, 0.f, 0.f, 0.f};
    f32x4 acc[4][4];
    #pragma unroll
    for (int i = 0; i < 4; ++i)
        #pragma unroll
        for (int j = 0; j < 4; ++j) acc[i][j] = zero;

    for (int ks = 0; ks < 4; ++ks) {
        #pragma unroll
        for (int i = 0; i < 4; ++i) {
            int c   = t + i * 256;           // 16B chunk id, 1024 per tile
            int row = c >> 3;
            int kg  = c & 7;
            int kgs = kg ^ (row & 7);        // write-side swizzle
            *(uint4*)(&As[row * BK + kgs * 8]) =
                *(const uint4*)(Abf + (size_t)(m0 + row) * 256 + ks * BK + kg * 8);
            *(uint4*)(&Bs[row * BK + kgs * 8]) =
                *(const uint4*)(Bbf + (size_t)(n0 + row) * 256 + ks * BK + kg * 8);
        }
        __syncthreads();
        #pragma unroll
        for (int k2 = 0; k2 < 2; ++k2) {
            bf16x8 av[4], bv[4];
            int kc = (l >> 4) + k2 * 4;
            #pragma unroll
            for (int i = 0; i < 4; ++i) {
                int ra = wr * 64 + i * 16 + (l & 15);
                av[i] = *(const bf16x8*)(&As[ra * BK + (kc ^ (ra & 7)) * 8]);
                int rb = wc * 64 + i * 16 + (l & 15);
                bv[i] = *(const bf16x8*)(&Bs[rb * BK + (kc ^ (rb & 7)) * 8]);
            }
            #pragma unroll
            for (int i = 0; i < 4; ++i)
                #pragma unroll
                for (int j = 0; j < 4; ++j)
                    acc[i][j] = __builtin_amdgcn_mfma_f32_16x16x32_bf16(av[i], bv[j], acc[i][j], 0, 0, 0);
        }
        __syncthreads();
    }

    // epilogue: ft (bf16) + fused el/er (wave's 64 cols == one head)
    int cb = n0 + wc * 64;
    int h  = cb >> 6;
    float wl[4], wrg[4];
    #pragma unroll
    for (int j = 0; j < 4; ++j) {
        int d = j * 16 + (l & 15);
        wl[j]  = attn_l[h * 64 + d];
        wrg[j] = attn_r[h * 64 + d];
    }
    int rbase = m0 + wr * 64;
    #pragma unroll
    for (int i = 0; i < 4; ++i) {
        #pragma unroll
        for (int r = 0; r < 4; ++r) {
            int m = rbase + i * 16 + (l >> 4) * 4 + r;
            float pl = 0.f, pr = 0.f;
            #pragma unroll
            for (int j = 0; j < 4; ++j) {
                float v = acc[i][j][r];
                ftbf[(size_t)m * 256 + cb + j * 16 + (l & 15)] = f2bf(v);
                pl = fmaf(v, wl[j], pl);
                pr = fmaf(v, wrg[j], pr);
            }
            #pragma unroll
            for (int s2 = 1; s2 <= 8; s2 <<= 1) {      // reduce 16 lanes (64 d's via 4 j's)
                pl += __shfl_xor(pl, s2, 64);
                pr += __shfl_xor(pr, s2, 64);
            }
            if ((l & 15) == 0 && m < N) { el[m * H + h] = pl; er[m * H + h] = pr; }
        }
    }
}

// ---------------- K2: in-degree count ----------------
__global__ void k_deg(const int* __restrict__ dst, unsigned* __restrict__ deg, int E) {
    int e = blockIdx.x * blockDim.x + threadIdx.x;
    if (e < E) atomicAdd(&deg[dst[e]], 1u);
}

// ---------------- K3: exclusive scan, thread-serial chunks ----------------
__global__ void k_scan(const unsigned* __restrict__ deg, unsigned* __restrict__ off, int n) {
    __shared__ unsigned part[1024];
    int t = threadIdx.x;
    int chunk = (n + 1023) >> 10;
    int b0 = t * chunk;
    int b1 = min(n, b0 + chunk);
    unsigned s = 0;
    for (int i = b0; i < b1; ++i) s += deg[i];
    part[t] = s;
    __syncthreads();
    for (int st = 1; st < 1024; st <<= 1) {
        unsigned add = (t >= st) ? part[t - st] : 0u;
        __syncthreads();
        part[t] += add;
        __syncthreads();
    }
    unsigned run = part[t] - s;        // exclusive
    for (int i = b0; i < b1; ++i) {
        unsigned d = deg[i];
        off[i] = run;
        run += d;
    }
    if (t == 1023) off[n] = run;
}

// ---------------- K4: scatter edge ids into CSR ----------------
__global__ void k_scatter(const int* __restrict__ dst, const unsigned* __restrict__ off,
                          unsigned* __restrict__ cursor, unsigned* __restrict__ sorted, int E) {
    int e = blockIdx.x * blockDim.x + threadIdx.x;
    if (e < E) {
        int d = dst[e];
        unsigned p = atomicAdd(&cursor[d], 1u);
        sorted[off[d] + p] = (unsigned)e;
    }
}

// ---------------- K5: per-edge logits -> exp ----------------
__global__ void k_logit(const int* __restrict__ efeat, const int* __restrict__ src,
                        const int* __restrict__ dst,
                        const float* __restrict__ el, const float* __restrict__ er,
                        const float* __restrict__ ee, float* __restrict__ ex, int E) {
    int g = blockIdx.x * blockDim.x + threadIdx.x;
    if (g >= E * H) return;
    int e = g >> 2, h = g & 3;
    float v = el[src[e] * H + h] + er[dst[e] * H + h] + ee[efeat[e] * H + h];
    v = v > 0.f ? v : NEG * v;
    ex[g] = expf(v);   // logits O(+-8); softmax is shift-invariant, no segment max needed
}

// ---------------- K6: wave-per-node softmax denom + gather-aggregate ----------------
__global__ void k_agg(const unsigned* __restrict__ off, const unsigned* __restrict__ sorted,
                      const int* __restrict__ src, const float* __restrict__ ex,
                      const ushort4* __restrict__ ft4, float4* __restrict__ out_rst4,
                      float* __restrict__ out_a, int N) {
    int wave = (int)((blockIdx.x * (size_t)blockDim.x + threadIdx.x) >> 6);
    if (wave >= N) return;
    int lane = threadIdx.x & 63;
    int h = lane >> 4;                      // 16 lanes per head
    unsigned beg = off[wave], end = off[wave + 1];

    float s = 0.f;
    for (unsigned j = beg; j < end; ++j) {
        unsigned eid = sorted[j];
        s += ex[eid * H + h];
    }
    float s0 = __shfl(s, 0, 64), s1 = __shfl(s, 16, 64),
          s2 = __shfl(s, 32, 64), s3 = __shfl(s, 48, 64);
    float inv  = (end > beg) ? 1.f / s : 0.f;
    float invw = 1.f;
    if (lane < 4) {
        float sw = (lane == 0) ? s0 : (lane == 1) ? s1 : (lane == 2) ? s2 : s3;
        invw = 1.f / sw;
    }

    float4 acc = make_float4(0.f, 0.f, 0.f, 0.f);
    for (unsigned j = beg; j < end; ++j) {
        unsigned eid = sorted[j];
        int sn = src[eid];
        float a = ex[eid * H + h] * inv;
        ushort4 f = ft4[(size_t)sn * 64 + lane];
        acc.x = fmaf(bf2f(f.x), a, acc.x);
        acc.y = fmaf(bf2f(f.y), a, acc.y);
        acc.z = fmaf(bf2f(f.z), a, acc.z);
        acc.w = fmaf(bf2f(f.w), a, acc.w);
        if (lane < 4) out_a[eid * H + lane] = ex[eid * H + lane] * invw;
    }
    out_rst4[(size_t)wave * 64 + lane] = acc;
}

extern "C" void kernel_launch(void* const* d_in, const int* in_sizes, int n_in,
                              void* d_out, int out_size, void* d_ws, size_t ws_size,
                              hipStream_t stream) {
    const float* feat     = (const float*)d_in[0];
    const int*   e_feat   = (const int*)d_in[1];
    const int*   src      = (const int*)d_in[2];
    const int*   dst      = (const int*)d_in[3];
    const float* W_fc     = (const float*)d_in[4];
    const float* edge_emb = (const float*)d_in[6];
    const float* W_e      = (const float*)d_in[5];
    const float* attn_l   = (const float*)d_in[7];
    const float* attn_r   = (const float*)d_in[8];
    const float* attn_e   = (const float*)d_in[9];

    int N = in_sizes[0] / IN_F;
    int E = in_sizes[1];
    int Mpad = ((N + BM - 1) / BM) * BM;

    float* out_rst = (float*)d_out;
    float* out_a   = out_rst + (size_t)N * C;

    // workspace layout
    ushort_t* featbf = (ushort_t*)d_ws;                  // Mpad*256 bf16
    ushort_t* WTbf   = featbf + (size_t)Mpad * 256;      // 256*256 bf16
    ushort_t* ftbf   = WTbf + 256 * 256;                 // Mpad*256 bf16
    float* el = (float*)(ftbf + (size_t)Mpad * 256);
    float* er = el + (size_t)N * H;
    float* ee = er + (size_t)N * H;
    float* ex = ee + 64;
    unsigned* deg    = (unsigned*)(ex + (size_t)E * H);
    unsigned* off    = deg + N;
    unsigned* cursor = off + (N + 1);
    unsigned* sorted = cursor + N;

    hipMemsetAsync(deg, 0, (size_t)N * sizeof(unsigned), stream);
    hipMemsetAsync(cursor, 0, (size_t)N * sizeof(unsigned), stream);

    k_etype  <<<8, 256, 0, stream>>>(edge_emb, W_e, attn_e, ee);
    k_featbf <<<(Mpad * 32 + 255) / 256, 256, 0, stream>>>(feat, featbf, N, Mpad);
    k_wt     <<<256, 256, 0, stream>>>(W_fc, WTbf);
    {
        dim3 grid(Mpad / BM, C / BN);
        k_gemm <<<grid, 256, 0, stream>>>(featbf, WTbf, attn_l, attn_r, ftbf, el, er, N);
    }
    k_deg    <<<(E + 255) / 256, 256, 0, stream>>>(dst, deg, E);
    k_scan   <<<1, 1024, 0, stream>>>(deg, off, N);
    k_scatter<<<(E + 255) / 256, 256, 0, stream>>>(dst, off, cursor, sorted, E);
    k_logit  <<<(E * H + 255) / 256, 256, 0, stream>>>(e_feat, src, dst, el, er, ee, ex, E);
    k_agg    <<<((size_t)N * 64 + 255) / 256, 256, 0, stream>>>(off, sorted, src, ex,
                                                                (const ushort4*)ftbf,
                                                                (float4*)out_rst, out_a, N);
}

// Round 3
// 432.305 us; speedup vs baseline: 1.9119x; 1.2749x over previous
//
#include <hip/hip_runtime.h>

#define H 4
#define D 64
#define C 256   // H*D
#define IN_F 256
#define EF 64
#define NEG 0.2f

typedef unsigned short ushort_t;
typedef __attribute__((ext_vector_type(8))) short bf16x8;
typedef __attribute__((ext_vector_type(4))) float f32x4;

__device__ __forceinline__ ushort_t f2bf(float x) {
    unsigned u = __float_as_uint(x);
    unsigned r = u + 0x7FFFu + ((u >> 16) & 1u);   // RNE
    return (ushort_t)(r >> 16);
}

// ---------------- K0: per-etype attention term ee[t][h] ----------------
__global__ void k_etype(const float* __restrict__ edge_emb, const float* __restrict__ W_e,
                        const float* __restrict__ attn_e, float* __restrict__ ee) {
    int t = blockIdx.x;          // etype 0..7
    int c = threadIdx.x;         // h*64+f
    float acc = 0.f;
    #pragma unroll 8
    for (int k = 0; k < EF; ++k)
        acc += edge_emb[t * EF + k] * W_e[k * C + c];
    acc *= attn_e[c];
    #pragma unroll
    for (int s = 32; s > 0; s >>= 1) acc += __shfl_down(acc, s, 64);
    if ((threadIdx.x & 63) == 0) ee[t * H + (threadIdx.x >> 6)] = acc;
}

// ---------------- K1a: feat f32 -> bf16 (padded rows zeroed) ----------------
__global__ void k_featbf(const float* __restrict__ feat, ushort_t* __restrict__ out,
                         int N, int Mpad) {
    int g = blockIdx.x * 256 + threadIdx.x;          // one per 8 elems
    int total = Mpad * 32;
    if (g >= total) return;
    int row = g >> 5;
    int c8 = (g & 31) * 8;
    ushort_t v[8];
    if (row < N) {
        float4 a = *(const float4*)(feat + (size_t)row * 256 + c8);
        float4 b = *(const float4*)(feat + (size_t)row * 256 + c8 + 4);
        v[0]=f2bf(a.x); v[1]=f2bf(a.y); v[2]=f2bf(a.z); v[3]=f2bf(a.w);
        v[4]=f2bf(b.x); v[5]=f2bf(b.y); v[6]=f2bf(b.z); v[7]=f2bf(b.w);
    } else {
        #pragma unroll
        for (int i = 0; i < 8; ++i) v[i] = 0;
    }
    *(uint4*)(out + (size_t)row * 256 + c8) = *(uint4*)v;
}

// ---------------- K1b: W_fc -> W^T bf16  (WT[n][k]) ----------------
__global__ void k_wt(const float* __restrict__ W, ushort_t* __restrict__ WT) {
    int n = blockIdx.x, k = threadIdx.x;
    WT[n * 256 + k] = f2bf(W[(size_t)k * 256 + n]);
}

// ---------------- K1c: GEMM ft = feat @ W_fc (bf16 MFMA), fused el/er ----------------
#define BM 128
#define BN 128
#define BK 64
__launch_bounds__(256, 2)
__global__ void k_gemm(const ushort_t* __restrict__ Abf, const ushort_t* __restrict__ Bbf,
                       const float* __restrict__ attn_l, const float* __restrict__ attn_r,
                       ushort_t* __restrict__ ftbf, float* __restrict__ el, float* __restrict__ er,
                       int N) {
    __shared__ ushort_t As[BM * BK];   // XOR-swizzled
    __shared__ ushort_t Bs[BN * BK];
    int t = threadIdx.x;
    int l = t & 63, w = t >> 6;
    int wr = w >> 1, wc = w & 1;       // 2x2 waves, 64x64 each
    int m0 = blockIdx.x * BM;
    int n0 = blockIdx.y * BN;

    f32x4 zero = {0.f, 0.f, 0.f, 0.f};
    f32x4 acc[4][4];
    #pragma unroll
    for (int i = 0; i < 4; ++i)
        #pragma unroll
        for (int j = 0; j < 4; ++j) acc[i][j] = zero;

    for (int ks = 0; ks < 4; ++ks) {
        #pragma unroll
        for (int i = 0; i < 4; ++i) {
            int c   = t + i * 256;
            int row = c >> 3;
            int kg  = c & 7;
            int kgs = kg ^ (row & 7);        // write-side swizzle
            *(uint4*)(&As[row * BK + kgs * 8]) =
                *(const uint4*)(Abf + (size_t)(m0 + row) * 256 + ks * BK + kg * 8);
            *(uint4*)(&Bs[row * BK + kgs * 8]) =
                *(const uint4*)(Bbf + (size_t)(n0 + row) * 256 + ks * BK + kg * 8);
        }
        __syncthreads();
        #pragma unroll
        for (int k2 = 0; k2 < 2; ++k2) {
            bf16x8 av[4], bv[4];
            int kc = (l >> 4) + k2 * 4;
            #pragma unroll
            for (int i = 0; i < 4; ++i) {
                int ra = wr * 64 + i * 16 + (l & 15);
                av[i] = *(const bf16x8*)(&As[ra * BK + (kc ^ (ra & 7)) * 8]);
                int rb = wc * 64 + i * 16 + (l & 15);
                bv[i] = *(const bf16x8*)(&Bs[rb * BK + (kc ^ (rb & 7)) * 8]);
            }
            #pragma unroll
            for (int i = 0; i < 4; ++i)
                #pragma unroll
                for (int j = 0; j < 4; ++j)
                    acc[i][j] = __builtin_amdgcn_mfma_f32_16x16x32_bf16(av[i], bv[j], acc[i][j], 0, 0, 0);
        }
        __syncthreads();
    }

    // epilogue: ft (bf16) + fused el/er (wave's 64 cols == one head)
    int cb = n0 + wc * 64;
    int h  = cb >> 6;
    float wl[4], wrg[4];
    #pragma unroll
    for (int j = 0; j < 4; ++j) {
        int d = j * 16 + (l & 15);
        wl[j]  = attn_l[h * 64 + d];
        wrg[j] = attn_r[h * 64 + d];
    }
    int rbase = m0 + wr * 64;
    #pragma unroll
    for (int i = 0; i < 4; ++i) {
        #pragma unroll
        for (int r = 0; r < 4; ++r) {
            int m = rbase + i * 16 + (l >> 4) * 4 + r;
            float pl = 0.f, pr = 0.f;
            #pragma unroll
            for (int j = 0; j < 4; ++j) {
                float v = acc[i][j][r];
                ftbf[(size_t)m * 256 + cb + j * 16 + (l & 15)] = f2bf(v);
                pl = fmaf(v, wl[j], pl);
                pr = fmaf(v, wrg[j], pr);
            }
            #pragma unroll
            for (int s2 = 1; s2 <= 8; s2 <<= 1) {
                pl += __shfl_xor(pl, s2, 64);
                pr += __shfl_xor(pr, s2, 64);
            }
            if ((l & 15) == 0 && m < N) { el[m * H + h] = pl; er[m * H + h] = pr; }
        }
    }
}

// ---------------- K2: in-degree count ----------------
__global__ void k_deg(const int* __restrict__ dst, unsigned* __restrict__ deg, int E) {
    int e = blockIdx.x * blockDim.x + threadIdx.x;
    if (e < E) atomicAdd(&deg[dst[e]], 1u);
}

// ---------------- K3: exclusive scan, thread-serial chunks ----------------
__global__ void k_scan(const unsigned* __restrict__ deg, unsigned* __restrict__ off, int n) {
    __shared__ unsigned part[1024];
    int t = threadIdx.x;
    int chunk = (n + 1023) >> 10;
    int b0 = t * chunk;
    int b1 = min(n, b0 + chunk);
    unsigned s = 0;
    for (int i = b0; i < b1; ++i) s += deg[i];
    part[t] = s;
    __syncthreads();
    for (int st = 1; st < 1024; st <<= 1) {
        unsigned add = (t >= st) ? part[t - st] : 0u;
        __syncthreads();
        part[t] += add;
        __syncthreads();
    }
    unsigned run = part[t] - s;        // exclusive
    for (int i = b0; i < b1; ++i) {
        unsigned d = deg[i];
        off[i] = run;
        run += d;
    }
    if (t == 1023) off[n] = run;
}

// ---------------- K4: scatter edges into CSR; emit pos + permuted src ----------------
__global__ void k_scatter(const int* __restrict__ dst, const int* __restrict__ src,
                          const unsigned* __restrict__ off,
                          unsigned* __restrict__ cursor, unsigned* __restrict__ sorted,
                          unsigned* __restrict__ pos, int* __restrict__ src_perm, int E) {
    int e = blockIdx.x * blockDim.x + threadIdx.x;
    if (e < E) {
        int d = dst[e];
        unsigned p = atomicAdd(&cursor[d], 1u);
        unsigned q = off[d] + p;
        sorted[q] = (unsigned)e;
        pos[e] = q;
        src_perm[q] = src[e];
    }
}

// ---------------- K5: per-edge logits -> exp, written in CSR order ----------------
__global__ void k_logit(const int* __restrict__ efeat, const int* __restrict__ src,
                        const int* __restrict__ dst,
                        const float4* __restrict__ el4, const float4* __restrict__ er4,
                        const float4* __restrict__ ee4, const unsigned* __restrict__ pos,
                        float4* __restrict__ exq, int E) {
    int e = blockIdx.x * blockDim.x + threadIdx.x;
    if (e >= E) return;
    float4 l = el4[src[e]];
    float4 r = er4[dst[e]];
    float4 te = ee4[efeat[e]];
    float4 v;
    v.x = l.x + r.x + te.x; v.y = l.y + r.y + te.y;
    v.z = l.z + r.z + te.z; v.w = l.w + r.w + te.w;
    v.x = v.x > 0.f ? v.x : NEG * v.x;
    v.y = v.y > 0.f ? v.y : NEG * v.y;
    v.z = v.z > 0.f ? v.z : NEG * v.z;
    v.w = v.w > 0.f ? v.w : NEG * v.w;
    v.x = __expf(v.x); v.y = __expf(v.y); v.z = __expf(v.z); v.w = __expf(v.w);
    exq[pos[e]] = v;      // logits O(+-8); softmax shift-invariant, no segment max
}

// ---------------- K6: wave-per-node softmax + gather-aggregate (2 edges/iter) ----------------
__device__ __forceinline__ void macc8(float* acc, uint4 f, float a) {
    unsigned u[4] = {f.x, f.y, f.z, f.w};
    #pragma unroll
    for (int q = 0; q < 4; ++q) {
        float lo = __uint_as_float(u[q] << 16);
        float hi = __uint_as_float(u[q] & 0xFFFF0000u);
        acc[2*q]   = fmaf(lo, a, acc[2*q]);
        acc[2*q+1] = fmaf(hi, a, acc[2*q+1]);
    }
}

__launch_bounds__(256)
__global__ void k_agg(const unsigned* __restrict__ off, const unsigned* __restrict__ sorted,
                      const int* __restrict__ src_perm, const float* __restrict__ exs,
                      const ushort_t* __restrict__ ft, float4* __restrict__ out4,
                      float* __restrict__ out_a, int N) {
    int node = (int)((blockIdx.x * (size_t)blockDim.x + threadIdx.x) >> 6);
    if (node >= N) return;
    int lane = threadIdx.x & 63;
    unsigned beg = off[node], end = off[node + 1];

    // ---- pass 1: denominators; contiguous CSR block, 16 edges/step ----
    int h1 = lane >> 4, i16 = lane & 15;
    float s = 0.f;
    for (unsigned j = beg + i16; j < end; j += 16)
        s += exs[j * 4 + h1];
    #pragma unroll
    for (int m = 1; m <= 8; m <<= 1) s += __shfl_xor(s, m, 64);
    float inv_h = (end > beg) ? 1.f / s : 0.f;         // this lane's head = h1

    int half = lane >> 5;            // which edge of the pair
    int cl   = lane & 31;            // col chunk: cols cl*8 .. cl*8+7
    int h2   = cl >> 3;              // head owning those cols
    float inv2 = __shfl(inv_h, h2 * 16, 64);           // denom for pass-2 cols
    float inva = __shfl(inv_h, (lane & 3) * 16, 64);   // denom for out_a writes

    float acc[8];
    #pragma unroll
    for (int q = 0; q < 8; ++q) acc[q] = 0.f;

    // ---- pass 2: two edges per iteration (half-wave each, 16B/lane) ----
    unsigned j = beg;
    for (; j + 1 < end; j += 2) {
        unsigned jj = j + half;
        int sn = src_perm[jj];
        uint4 f = *(const uint4*)(ft + (size_t)sn * 256 + cl * 8);
        float a = exs[jj * 4 + h2] * inv2;
        macc8(acc, f, a);
        if (cl < 4) {
            unsigned eid = sorted[jj];
            out_a[eid * 4 + cl] = exs[jj * 4 + cl] * inva;
        }
    }
    if (j < end) {                   // odd tail: lanes 32-63 contribute zero
        int sn = src_perm[j];
        uint4 f = *(const uint4*)(ft + (size_t)sn * 256 + cl * 8);
        float a = (half == 0) ? exs[j * 4 + h2] * inv2 : 0.f;
        macc8(acc, f, a);
        if (lane < 4) {
            unsigned eid = sorted[j];
            out_a[eid * 4 + lane] = exs[j * 4 + lane] * inva;
        }
    }

    // combine the two halves, lanes 0-31 write the row
    #pragma unroll
    for (int q = 0; q < 8; ++q) acc[q] += __shfl_xor(acc[q], 32, 64);
    if (half == 0) {
        float4 o0 = {acc[0], acc[1], acc[2], acc[3]};
        float4 o1 = {acc[4], acc[5], acc[6], acc[7]};
        out4[(size_t)node * 64 + cl * 2]     = o0;
        out4[(size_t)node * 64 + cl * 2 + 1] = o1;
    }
}

extern "C" void kernel_launch(void* const* d_in, const int* in_sizes, int n_in,
                              void* d_out, int out_size, void* d_ws, size_t ws_size,
                              hipStream_t stream) {
    const float* feat     = (const float*)d_in[0];
    const int*   e_feat   = (const int*)d_in[1];
    const int*   src      = (const int*)d_in[2];
    const int*   dst      = (const int*)d_in[3];
    const float* W_fc     = (const float*)d_in[4];
    const float* W_e      = (const float*)d_in[5];
    const float* edge_emb = (const float*)d_in[6];
    const float* attn_l   = (const float*)d_in[7];
    const float* attn_r   = (const float*)d_in[8];
    const float* attn_e   = (const float*)d_in[9];

    int N = in_sizes[0] / IN_F;
    int E = in_sizes[1];
    int Mpad = ((N + BM - 1) / BM) * BM;

    float* out_rst = (float*)d_out;
    float* out_a   = out_rst + (size_t)N * C;

    // workspace layout
    ushort_t* featbf = (ushort_t*)d_ws;                  // Mpad*256 bf16 (dead after k_gemm)
    ushort_t* WTbf   = featbf + (size_t)Mpad * 256;      // 256*256 bf16
    ushort_t* ftbf   = WTbf + 256 * 256;                 // Mpad*256 bf16
    float* el = (float*)(ftbf + (size_t)Mpad * 256);     // N*4
    float* er = el + (size_t)N * H;                      // N*4
    float* ee = er + (size_t)N * H;                      // 64 (32 used)
    unsigned* deg    = (unsigned*)(ee + 64);
    unsigned* off    = deg + N;
    unsigned* cursor = off + (N + 1);
    unsigned* sorted = cursor + N;
    unsigned* pos    = sorted + E;
    int* src_perm    = (int*)(pos + E);
    float4* exq      = (float4*)featbf;                  // alias: reused after k_gemm

    hipMemsetAsync(deg, 0, (size_t)N * sizeof(unsigned), stream);
    hipMemsetAsync(cursor, 0, (size_t)N * sizeof(unsigned), stream);

    k_etype  <<<8, 256, 0, stream>>>(edge_emb, W_e, attn_e, ee);
    k_featbf <<<(Mpad * 32 + 255) / 256, 256, 0, stream>>>(feat, featbf, N, Mpad);
    k_wt     <<<256, 256, 0, stream>>>(W_fc, WTbf);
    {
        dim3 grid(Mpad / BM, C / BN);
        k_gemm <<<grid, 256, 0, stream>>>(featbf, WTbf, attn_l, attn_r, ftbf, el, er, N);
    }
    k_deg    <<<(E + 255) / 256, 256, 0, stream>>>(dst, deg, E);
    k_scan   <<<1, 1024, 0, stream>>>(deg, off, N);
    k_scatter<<<(E + 255) / 256, 256, 0, stream>>>(dst, src, off, cursor, sorted, pos, src_perm, E);
    k_logit  <<<(E + 255) / 256, 256, 0, stream>>>(e_feat, src, dst,
                                                   (const float4*)el, (const float4*)er,
                                                   (const float4*)ee, pos, exq, E);
    k_agg    <<<((size_t)N * 64 + 255) / 256, 256, 0, stream>>>(off, sorted, src_perm,
                                                                (const float*)exq, ftbf,
                                                                (float4*)out_rst, out_a, N);
}

// Round 4
// 328.639 us; speedup vs baseline: 2.5150x; 1.3154x over previous
//
#include <hip/hip_runtime.h>

#define H 4
#define D 64
#define C 256   // H*D
#define IN_F 256
#define EF 64
#define NEG 0.2f

typedef unsigned short ushort_t;
typedef __attribute__((ext_vector_type(8))) short bf16x8;
typedef __attribute__((ext_vector_type(4))) float f32x4;

__device__ __forceinline__ ushort_t f2bf(float x) {
    unsigned u = __float_as_uint(x);
    unsigned r = u + 0x7FFFu + ((u >> 16) & 1u);   // RNE
    return (ushort_t)(r >> 16);
}

// ---------------- K0: per-etype attention term ee[t][h] ----------------
__global__ void k_etype(const float* __restrict__ edge_emb, const float* __restrict__ W_e,
                        const float* __restrict__ attn_e, float* __restrict__ ee) {
    int t = blockIdx.x;          // etype 0..7
    int c = threadIdx.x;         // h*64+f
    float acc = 0.f;
    #pragma unroll 8
    for (int k = 0; k < EF; ++k)
        acc += edge_emb[t * EF + k] * W_e[k * C + c];
    acc *= attn_e[c];
    #pragma unroll
    for (int s = 32; s > 0; s >>= 1) acc += __shfl_down(acc, s, 64);
    if ((threadIdx.x & 63) == 0) ee[t * H + (threadIdx.x >> 6)] = acc;
}

// ---------------- K1b: W_fc -> W^T bf16  (WT[n][k]) ----------------
__global__ void k_wt(const float* __restrict__ W, ushort_t* __restrict__ WT) {
    int n = blockIdx.x, k = threadIdx.x;
    WT[n * 256 + k] = f2bf(W[(size_t)k * 256 + n]);
}

// ---------------- K1c: GEMM ft = feat @ W_fc (bf16 MFMA), A converted on the fly ----------------
#define BM 128
#define BN 128
#define BK 64
__launch_bounds__(256, 2)
__global__ void k_gemm(const float* __restrict__ feat, const ushort_t* __restrict__ Bbf,
                       const float* __restrict__ attn_l, const float* __restrict__ attn_r,
                       ushort_t* __restrict__ ftbf, float* __restrict__ el, float* __restrict__ er,
                       int N) {
    __shared__ ushort_t As[BM * BK];   // XOR-swizzled chunk (row, kg^(row&7))
    __shared__ ushort_t Bs[BN * BK];
    int t = threadIdx.x;
    int l = t & 63, w = t >> 6;
    int wr = w >> 1, wc = w & 1;       // 2x2 waves, 64x64 each
    int m0 = blockIdx.x * BM;
    int n0 = blockIdx.y * BN;

    f32x4 zero = {0.f, 0.f, 0.f, 0.f};
    f32x4 acc[4][4];
    #pragma unroll
    for (int i = 0; i < 4; ++i)
        #pragma unroll
        for (int j = 0; j < 4; ++j) acc[i][j] = zero;

    for (int ks = 0; ks < 4; ++ks) {
        #pragma unroll
        for (int i = 0; i < 4; ++i) {
            int c   = t + i * 256;
            int row = c >> 3;
            int kg  = c & 7;
            int kgs = kg ^ (row & 7);        // write-side swizzle
            // A: load f32, convert to bf16 in regs, store swizzled
            int gr = m0 + row;
            float4 a0 = {0.f,0.f,0.f,0.f}, a1 = {0.f,0.f,0.f,0.f};
            if (gr < N) {
                const float* ap = feat + (size_t)gr * 256 + ks * BK + kg * 8;
                a0 = *(const float4*)ap;
                a1 = *(const float4*)(ap + 4);
            }
            ushort_t v[8];
            v[0]=f2bf(a0.x); v[1]=f2bf(a0.y); v[2]=f2bf(a0.z); v[3]=f2bf(a0.w);
            v[4]=f2bf(a1.x); v[5]=f2bf(a1.y); v[6]=f2bf(a1.z); v[7]=f2bf(a1.w);
            *(uint4*)(&As[row * BK + kgs * 8]) = *(uint4*)v;
            // B: already bf16
            *(uint4*)(&Bs[row * BK + kgs * 8]) =
                *(const uint4*)(Bbf + (size_t)(n0 + row) * 256 + ks * BK + kg * 8);
        }
        __syncthreads();
        #pragma unroll
        for (int k2 = 0; k2 < 2; ++k2) {
            bf16x8 av[4], bv[4];
            int kc = (l >> 4) + k2 * 4;
            #pragma unroll
            for (int i = 0; i < 4; ++i) {
                int ra = wr * 64 + i * 16 + (l & 15);
                av[i] = *(const bf16x8*)(&As[ra * BK + (kc ^ (ra & 7)) * 8]);
                int rb = wc * 64 + i * 16 + (l & 15);
                bv[i] = *(const bf16x8*)(&Bs[rb * BK + (kc ^ (rb & 7)) * 8]);
            }
            #pragma unroll
            for (int i = 0; i < 4; ++i)
                #pragma unroll
                for (int j = 0; j < 4; ++j)
                    acc[i][j] = __builtin_amdgcn_mfma_f32_16x16x32_bf16(av[i], bv[j], acc[i][j], 0, 0, 0);
        }
        __syncthreads();
    }

    // epilogue: ft (bf16) + fused el/er (wave's 64 cols == one head)
    int cb = n0 + wc * 64;
    int h  = cb >> 6;
    float wl[4], wrg[4];
    #pragma unroll
    for (int j = 0; j < 4; ++j) {
        int d = j * 16 + (l & 15);
        wl[j]  = attn_l[h * 64 + d];
        wrg[j] = attn_r[h * 64 + d];
    }
    int rbase = m0 + wr * 64;
    #pragma unroll
    for (int i = 0; i < 4; ++i) {
        #pragma unroll
        for (int r = 0; r < 4; ++r) {
            int m = rbase + i * 16 + (l >> 4) * 4 + r;
            float pl = 0.f, pr = 0.f;
            #pragma unroll
            for (int j = 0; j < 4; ++j) {
                float v = acc[i][j][r];
                ftbf[(size_t)m * 256 + cb + j * 16 + (l & 15)] = f2bf(v);
                pl = fmaf(v, wl[j], pl);
                pr = fmaf(v, wrg[j], pr);
            }
            #pragma unroll
            for (int s2 = 1; s2 <= 8; s2 <<= 1) {
                pl += __shfl_xor(pl, s2, 64);
                pr += __shfl_xor(pr, s2, 64);
            }
            if ((l & 15) == 0 && m < N) { el[m * H + h] = pl; er[m * H + h] = pr; }
        }
    }
}

// ---------------- K2: in-degree count (4 edges/thread) ----------------
__global__ void k_deg(const int* __restrict__ dst, unsigned* __restrict__ deg, int E) {
    int i = (blockIdx.x * 256 + threadIdx.x) * 4;
    if (i + 3 < E) {
        int4 d = *(const int4*)(dst + i);
        atomicAdd(&deg[d.x], 1u); atomicAdd(&deg[d.y], 1u);
        atomicAdd(&deg[d.z], 1u); atomicAdd(&deg[d.w], 1u);
    } else {
        for (int k = 0; k < 4; ++k)
            if (i + k < E) atomicAdd(&deg[dst[i + k]], 1u);
    }
}

// ---------------- K3: exclusive scan (coalesced, wave-shfl + LDS) ----------------
// produces off[0..n]; treats deg[i>=n] as 0; pads stores to 4096-tile boundary.
__global__ void k_scan(const unsigned* __restrict__ deg, unsigned* __restrict__ off, int n) {
    __shared__ unsigned wsum[16];
    __shared__ unsigned carry_s;
    int t = threadIdx.x;
    int lane = t & 63, wv = t >> 6;
    if (t == 0) carry_s = 0;
    __syncthreads();
    int ns = n + 1;
    int ntile = (ns + 4095) >> 12;
    for (int tile = 0; tile < ntile; ++tile) {
        int i0 = (tile << 12) + t * 4;
        uint4 v;
        if (i0 + 3 < n) {
            v = *(const uint4*)(deg + i0);
        } else {
            v.x = (i0 + 0 < n) ? deg[i0 + 0] : 0u;
            v.y = (i0 + 1 < n) ? deg[i0 + 1] : 0u;
            v.z = (i0 + 2 < n) ? deg[i0 + 2] : 0u;
            v.w = (i0 + 3 < n) ? deg[i0 + 3] : 0u;
        }
        unsigned s = v.x + v.y + v.z + v.w;
        unsigned sc = s;
        #pragma unroll
        for (int d = 1; d < 64; d <<= 1) {
            unsigned u = __shfl_up(sc, d, 64);
            if (lane >= d) sc += u;
        }
        if (lane == 63) wsum[wv] = sc;
        __syncthreads();
        unsigned carry = carry_s;
        unsigned woff = 0;
        #pragma unroll
        for (int k = 0; k < 16; ++k) woff += (k < wv) ? wsum[k] : 0u;
        unsigned ex0 = carry + woff + sc - s;   // exclusive prefix at i0
        uint4 o;
        o.x = ex0; o.y = ex0 + v.x; o.z = o.y + v.y; o.w = o.z + v.z;
        *(uint4*)(off + i0) = o;                // off padded to tile boundary
        __syncthreads();
        if (t == 1023) carry_s = carry + woff + sc;
    }
}

// ---------------- K4: fused scatter + logit: CSR place, exp(lrelu), es record ----------------
__global__ void k_scatlog(const int* __restrict__ dst, const int* __restrict__ src,
                          const int* __restrict__ efeat, const unsigned* __restrict__ off,
                          unsigned* __restrict__ cursor,
                          const float4* __restrict__ el4, const float4* __restrict__ er4,
                          const float4* __restrict__ ee4,
                          float4* __restrict__ exq, uint2* __restrict__ es, int E) {
    int e = blockIdx.x * 256 + threadIdx.x;
    if (e >= E) return;
    int d = dst[e], s = src[e];
    unsigned q = off[d] + atomicAdd(&cursor[d], 1u);
    float4 l = el4[s];
    float4 r = er4[d];
    float4 te = ee4[efeat[e]];
    float4 v;
    v.x = l.x + r.x + te.x; v.y = l.y + r.y + te.y;
    v.z = l.z + r.z + te.z; v.w = l.w + r.w + te.w;
    v.x = v.x > 0.f ? v.x : NEG * v.x;
    v.y = v.y > 0.f ? v.y : NEG * v.y;
    v.z = v.z > 0.f ? v.z : NEG * v.z;
    v.w = v.w > 0.f ? v.w : NEG * v.w;
    v.x = __expf(v.x); v.y = __expf(v.y); v.z = __expf(v.z); v.w = __expf(v.w);
    exq[q] = v;                         // logits O(+-8); softmax shift-invariant
    es[q] = make_uint2((unsigned)e, (unsigned)s);
}

// ---------------- K6: wave-per-node softmax + pipelined gather-aggregate ----------------
__device__ __forceinline__ void macc8(float* acc, uint4 f, float a) {
    unsigned u[4] = {f.x, f.y, f.z, f.w};
    #pragma unroll
    for (int q = 0; q < 4; ++q) {
        float lo = __uint_as_float(u[q] << 16);
        float hi = __uint_as_float(u[q] & 0xFFFF0000u);
        acc[2*q]   = fmaf(lo, a, acc[2*q]);
        acc[2*q+1] = fmaf(hi, a, acc[2*q+1]);
    }
}

__launch_bounds__(256)
__global__ void k_agg(const unsigned* __restrict__ off, const uint2* __restrict__ es,
                      const float* __restrict__ exs, const ushort_t* __restrict__ ft,
                      float4* __restrict__ out4, float* __restrict__ out_a, int N) {
    int node = (int)((blockIdx.x * (size_t)blockDim.x + threadIdx.x) >> 6);
    if (node >= N) return;
    int lane = threadIdx.x & 63;
    unsigned beg = off[node], end = off[node + 1];

    // ---- pass 1: denominators; contiguous CSR block, 16 edges/step ----
    int h1 = lane >> 4, i16 = lane & 15;
    float s = 0.f;
    for (unsigned j = beg + i16; j < end; j += 16)
        s += exs[j * 4 + h1];
    #pragma unroll
    for (int m = 1; m <= 8; m <<= 1) s += __shfl_xor(s, m, 64);
    float inv_h = (end > beg) ? 1.f / s : 0.f;         // lane's head = h1

    int half = lane >> 5;            // which edge of the pair
    int cl   = lane & 31;            // col chunk: cols cl*8 .. cl*8+7
    int h2   = cl >> 3;              // head owning those cols
    float inv2 = __shfl(inv_h, h2 * 16, 64);           // denom for pass-2 cols
    float inva = __shfl(inv_h, (lane & 3) * 16, 64);   // denom for out_a writes

    float acc[8];
    #pragma unroll
    for (int q = 0; q < 8; ++q) acc[q] = 0.f;

    // ---- pass 2: two edges/iter, es prefetched one iteration ahead ----
    unsigned j = beg;
    uint2 cur;
    if (j + half < end) cur = es[j + half];
    for (; j + 1 < end; j += 2) {
        unsigned jj = j + half;
        uint2 e2 = cur;
        float a  = exs[jj * 4 + h2] * inv2;
        float aw = exs[jj * 4 + (lane & 3)];
        unsigned jn = jj + 2;
        if (jn < end) cur = es[jn];                    // prefetch next pair
        uint4 f = *(const uint4*)(ft + (size_t)e2.y * 256 + cl * 8);
        macc8(acc, f, a);
        if (cl < 4) out_a[e2.x * 4 + cl] = aw * inva;
    }
    if (j < end) {                   // odd tail: half==1 lanes contribute zero
        uint2 e2 = es[j];
        float a = (half == 0) ? exs[j * 4 + h2] * inv2 : 0.f;
        uint4 f = *(const uint4*)(ft + (size_t)e2.y * 256 + cl * 8);
        macc8(acc, f, a);
        if (lane < 4) out_a[e2.x * 4 + lane] = exs[j * 4 + lane] * inva;
    }

    // combine halves; lanes 0-31 write the row
    #pragma unroll
    for (int q = 0; q < 8; ++q) acc[q] += __shfl_xor(acc[q], 32, 64);
    if (half == 0) {
        float4 o0 = {acc[0], acc[1], acc[2], acc[3]};
        float4 o1 = {acc[4], acc[5], acc[6], acc[7]};
        out4[(size_t)node * 64 + cl * 2]     = o0;
        out4[(size_t)node * 64 + cl * 2 + 1] = o1;
    }
}

extern "C" void kernel_launch(void* const* d_in, const int* in_sizes, int n_in,
                              void* d_out, int out_size, void* d_ws, size_t ws_size,
                              hipStream_t stream) {
    const float* feat     = (const float*)d_in[0];
    const int*   e_feat   = (const int*)d_in[1];
    const int*   src      = (const int*)d_in[2];
    const int*   dst      = (const int*)d_in[3];
    const float* W_fc     = (const float*)d_in[4];
    const float* W_e      = (const float*)d_in[5];
    const float* edge_emb = (const float*)d_in[6];
    const float* attn_l   = (const float*)d_in[7];
    const float* attn_r   = (const float*)d_in[8];
    const float* attn_e   = (const float*)d_in[9];

    int N = in_sizes[0] / IN_F;
    int E = in_sizes[1];
    int Mpad = ((N + BM - 1) / BM) * BM;
    int Npad4  = (N + 3) & ~3;
    int offpad = (((N + 1) + 4095) >> 12) << 12;   // scan writes full 4096 tiles
    int Epad2  = (E + 1) & ~1;

    float* out_rst = (float*)d_out;
    float* out_a   = out_rst + (size_t)N * C;

    // workspace layout (16B-aligned sections)
    ushort_t* WTbf = (ushort_t*)d_ws;                    // 256*256 bf16
    ushort_t* ftbf = WTbf + 256 * 256;                   // Mpad*256 bf16
    float* el = (float*)(ftbf + (size_t)Mpad * 256);     // N*4
    float* er = el + (size_t)N * H;                      // N*4
    float* ee = er + (size_t)N * H;                      // 64 (32 used)
    unsigned* deg    = (unsigned*)(ee + 64);             // Npad4
    unsigned* off    = deg + Npad4;                      // offpad
    unsigned* cursor = off + offpad;                     // Npad4
    uint2*    es     = (uint2*)(cursor + Npad4);         // Epad2
    float4*   exq    = (float4*)(es + Epad2);            // E

    hipMemsetAsync(deg, 0, (size_t)Npad4 * sizeof(unsigned), stream);
    hipMemsetAsync(cursor, 0, (size_t)Npad4 * sizeof(unsigned), stream);

    k_etype  <<<8, 256, 0, stream>>>(edge_emb, W_e, attn_e, ee);
    k_wt     <<<256, 256, 0, stream>>>(W_fc, WTbf);
    {
        dim3 grid(Mpad / BM, C / BN);
        k_gemm <<<grid, 256, 0, stream>>>(feat, WTbf, attn_l, attn_r, ftbf, el, er, N);
    }
    k_deg    <<<(E / 4 + 255) / 256, 256, 0, stream>>>(dst, deg, E);
    k_scan   <<<1, 1024, 0, stream>>>(deg, off, N);
    k_scatlog<<<(E + 255) / 256, 256, 0, stream>>>(dst, src, e_feat, off, cursor,
                                                   (const float4*)el, (const float4*)er,
                                                   (const float4*)ee, exq, es, E);
    k_agg    <<<((size_t)N * 64 + 255) / 256, 256, 0, stream>>>(off, es, (const float*)exq,
                                                                ftbf, (float4*)out_rst, out_a, N);
}

// Round 5
// 309.808 us; speedup vs baseline: 2.6679x; 1.0608x over previous
//
#include <hip/hip_runtime.h>

#define H 4
#define D 64
#define C 256   // H*D
#define IN_F 256
#define EF 64
#define NEG 0.2f

typedef unsigned short ushort_t;
typedef __attribute__((ext_vector_type(8))) short bf16x8;
typedef __attribute__((ext_vector_type(4))) float f32x4;

__device__ __forceinline__ ushort_t f2bf(float x) {
    unsigned u = __float_as_uint(x);
    unsigned r = u + 0x7FFFu + ((u >> 16) & 1u);   // RNE
    return (ushort_t)(r >> 16);
}

// ---------------- K0: fused {W_fc transpose -> bf16} + {per-etype ee} ----------------
// blocks 0..15: 64x64 tile transpose of W (coalesced read+write via LDS)
// blocks 16..23: etype term ee[t][h]
__global__ void k_misc(const float* __restrict__ W, ushort_t* __restrict__ WT,
                       const float* __restrict__ edge_emb, const float* __restrict__ W_e,
                       const float* __restrict__ attn_e, float* __restrict__ ee) {
    int b = blockIdx.x;
    if (b < 16) {
        __shared__ float tile[64][65];
        int bi = b >> 2, bj = b & 3;           // W rows bi*64.., cols bj*64..
        int lane = threadIdx.x & 63, wv = threadIdx.x >> 6;
        #pragma unroll
        for (int i = 0; i < 16; ++i) {
            int row = wv * 16 + i;
            tile[row][lane] = W[(size_t)(bi * 64 + row) * 256 + bj * 64 + lane];
        }
        __syncthreads();
        #pragma unroll
        for (int i = 0; i < 16; ++i) {
            int row = wv * 16 + i;             // WT row = bj*64+row
            WT[(size_t)(bj * 64 + row) * 256 + bi * 64 + lane] = f2bf(tile[lane][row]);
        }
    } else {
        int t = b - 16;                        // etype 0..7
        int c = threadIdx.x;
        float acc = 0.f;
        #pragma unroll 8
        for (int k = 0; k < EF; ++k)
            acc += edge_emb[t * EF + k] * W_e[k * C + c];
        acc *= attn_e[c];
        #pragma unroll
        for (int s = 32; s > 0; s >>= 1) acc += __shfl_down(acc, s, 64);
        if ((threadIdx.x & 63) == 0) ee[t * H + (threadIdx.x >> 6)] = acc;
    }
}

// ---------------- K1: GEMM ft = feat @ W_fc (bf16 MFMA), BN=256, fused el/er ----------------
#define BM 128
#define BK 64
__launch_bounds__(512)
__global__ void k_gemm(const float* __restrict__ feat, const ushort_t* __restrict__ Bbf,
                       const float* __restrict__ attn_l, const float* __restrict__ attn_r,
                       ushort_t* __restrict__ ftbf, float* __restrict__ el, float* __restrict__ er,
                       int N) {
    __shared__ ushort_t As[BM * BK];   // XOR-swizzled chunk (row, kg^(row&7))
    __shared__ ushort_t Bs[C * BK];
    int t = threadIdx.x;
    int l = t & 63, w = t >> 6;
    int wr = w >> 2, wc = w & 3;       // 2x4 waves, 64x64 tiles
    int m0 = blockIdx.x * BM;

    f32x4 zero = {0.f, 0.f, 0.f, 0.f};
    f32x4 acc[4][4];
    #pragma unroll
    for (int i = 0; i < 4; ++i)
        #pragma unroll
        for (int j = 0; j < 4; ++j) acc[i][j] = zero;

    for (int ks = 0; ks < 4; ++ks) {
        // stage A (1024 chunks): f32 -> bf16 in regs, swizzled LDS write
        #pragma unroll
        for (int i = 0; i < 2; ++i) {
            int c   = t + i * 512;
            int row = c >> 3;
            int kg  = c & 7;
            int kgs = kg ^ (row & 7);
            int gr = m0 + row;
            float4 a0 = {0.f,0.f,0.f,0.f}, a1 = {0.f,0.f,0.f,0.f};
            if (gr < N) {
                const float* ap = feat + (size_t)gr * 256 + ks * BK + kg * 8;
                a0 = *(const float4*)ap;
                a1 = *(const float4*)(ap + 4);
            }
            ushort_t v[8];
            v[0]=f2bf(a0.x); v[1]=f2bf(a0.y); v[2]=f2bf(a0.z); v[3]=f2bf(a0.w);
            v[4]=f2bf(a1.x); v[5]=f2bf(a1.y); v[6]=f2bf(a1.z); v[7]=f2bf(a1.w);
            *(uint4*)(&As[row * BK + kgs * 8]) = *(uint4*)v;
        }
        // stage B (2048 chunks): bf16 passthrough
        #pragma unroll
        for (int i = 0; i < 4; ++i) {
            int c   = t + i * 512;
            int row = c >> 3;
            int kg  = c & 7;
            int kgs = kg ^ (row & 7);
            *(uint4*)(&Bs[row * BK + kgs * 8]) =
                *(const uint4*)(Bbf + (size_t)row * 256 + ks * BK + kg * 8);
        }
        __syncthreads();
        #pragma unroll
        for (int k2 = 0; k2 < 2; ++k2) {
            bf16x8 av[4], bv[4];
            int kc = (l >> 4) + k2 * 4;
            #pragma unroll
            for (int i = 0; i < 4; ++i) {
                int ra = wr * 64 + i * 16 + (l & 15);
                av[i] = *(const bf16x8*)(&As[ra * BK + (kc ^ (ra & 7)) * 8]);
                int rb = wc * 64 + i * 16 + (l & 15);
                bv[i] = *(const bf16x8*)(&Bs[rb * BK + (kc ^ (rb & 7)) * 8]);
            }
            #pragma unroll
            for (int i = 0; i < 4; ++i)
                #pragma unroll
                for (int j = 0; j < 4; ++j)
                    acc[i][j] = __builtin_amdgcn_mfma_f32_16x16x32_bf16(av[i], bv[j], acc[i][j], 0, 0, 0);
        }
        __syncthreads();
    }

    // epilogue: ft (bf16) + fused el/er (wave's 64 cols == one head)
    int cb = wc * 64;
    int h  = wc;
    float wl[4], wrg[4];
    #pragma unroll
    for (int j = 0; j < 4; ++j) {
        int d = j * 16 + (l & 15);
        wl[j]  = attn_l[h * 64 + d];
        wrg[j] = attn_r[h * 64 + d];
    }
    int rbase = m0 + wr * 64;
    #pragma unroll
    for (int i = 0; i < 4; ++i) {
        #pragma unroll
        for (int r = 0; r < 4; ++r) {
            int m = rbase + i * 16 + (l >> 4) * 4 + r;
            float pl = 0.f, pr = 0.f;
            #pragma unroll
            for (int j = 0; j < 4; ++j) {
                float v = acc[i][j][r];
                ftbf[(size_t)m * 256 + cb + j * 16 + (l & 15)] = f2bf(v);
                pl = fmaf(v, wl[j], pl);
                pr = fmaf(v, wrg[j], pr);
            }
            #pragma unroll
            for (int s2 = 1; s2 <= 8; s2 <<= 1) {
                pl += __shfl_xor(pl, s2, 64);
                pr += __shfl_xor(pr, s2, 64);
            }
            if ((l & 15) == 0 && m < N) { el[m * H + h] = pl; er[m * H + h] = pr; }
        }
    }
}

// ---------------- K2: in-degree count (4 edges/thread) ----------------
__global__ void k_deg(const int* __restrict__ dst, unsigned* __restrict__ deg, int E) {
    int i = (blockIdx.x * 256 + threadIdx.x) * 4;
    if (i + 3 < E) {
        int4 d = *(const int4*)(dst + i);
        atomicAdd(&deg[d.x], 1u); atomicAdd(&deg[d.y], 1u);
        atomicAdd(&deg[d.z], 1u); atomicAdd(&deg[d.w], 1u);
    } else {
        for (int k = 0; k < 4; ++k)
            if (i + k < E) atomicAdd(&deg[dst[i + k]], 1u);
    }
}

// ---------------- K3: exclusive scan -> off AND cursor (coalesced) ----------------
__global__ void k_scan(const unsigned* __restrict__ deg, unsigned* __restrict__ off,
                       unsigned* __restrict__ cursor, int n) {
    __shared__ unsigned wsum[16];
    __shared__ unsigned carry_s;
    int t = threadIdx.x;
    int lane = t & 63, wv = t >> 6;
    if (t == 0) carry_s = 0;
    __syncthreads();
    int ns = n + 1;
    int ntile = (ns + 4095) >> 12;
    for (int tile = 0; tile < ntile; ++tile) {
        int i0 = (tile << 12) + t * 4;
        uint4 v;
        if (i0 + 3 < n) {
            v = *(const uint4*)(deg + i0);
        } else {
            v.x = (i0 + 0 < n) ? deg[i0 + 0] : 0u;
            v.y = (i0 + 1 < n) ? deg[i0 + 1] : 0u;
            v.z = (i0 + 2 < n) ? deg[i0 + 2] : 0u;
            v.w = (i0 + 3 < n) ? deg[i0 + 3] : 0u;
        }
        unsigned s = v.x + v.y + v.z + v.w;
        unsigned sc = s;
        #pragma unroll
        for (int d = 1; d < 64; d <<= 1) {
            unsigned u = __shfl_up(sc, d, 64);
            if (lane >= d) sc += u;
        }
        if (lane == 63) wsum[wv] = sc;
        __syncthreads();
        unsigned carry = carry_s;
        unsigned woff = 0;
        #pragma unroll
        for (int k = 0; k < 16; ++k) woff += (k < wv) ? wsum[k] : 0u;
        unsigned ex0 = carry + woff + sc - s;   // exclusive prefix at i0
        uint4 o;
        o.x = ex0; o.y = ex0 + v.x; o.z = o.y + v.y; o.w = o.z + v.z;
        *(uint4*)(off + i0) = o;                // regions padded to tile boundary
        *(uint4*)(cursor + i0) = o;             // cursor starts at off
        __syncthreads();
        if (t == 1023) carry_s = carry + woff + sc;
    }
}

// ---------------- K4: fused scatter+logit: atomic CSR place, exp(lrelu), es record ----------------
__global__ void k_scatlog(const int* __restrict__ dst, const int* __restrict__ src,
                          const int* __restrict__ efeat,
                          unsigned* __restrict__ cursor,
                          const float4* __restrict__ el4, const float4* __restrict__ er4,
                          const float4* __restrict__ ee4,
                          float4* __restrict__ exq, uint2* __restrict__ es, int E) {
    int e = blockIdx.x * 256 + threadIdx.x;
    if (e >= E) return;
    int d = dst[e], s = src[e];
    unsigned q = atomicAdd(&cursor[d], 1u);     // cursor pre-seeded with off
    float4 l = el4[s];
    float4 r = er4[d];
    float4 te = ee4[efeat[e]];
    float4 v;
    v.x = l.x + r.x + te.x; v.y = l.y + r.y + te.y;
    v.z = l.z + r.z + te.z; v.w = l.w + r.w + te.w;
    v.x = v.x > 0.f ? v.x : NEG * v.x;
    v.y = v.y > 0.f ? v.y : NEG * v.y;
    v.z = v.z > 0.f ? v.z : NEG * v.z;
    v.w = v.w > 0.f ? v.w : NEG * v.w;
    v.x = __expf(v.x); v.y = __expf(v.y); v.z = __expf(v.z); v.w = __expf(v.w);
    exq[q] = v;                         // logits O(+-8); softmax shift-invariant
    es[q] = make_uint2((unsigned)e, (unsigned)s);
}

// ---------------- K5: wave-per-node softmax + 4-edge/iter gather-aggregate ----------------
__device__ __forceinline__ void macc8(float* acc, uint4 f, float a) {
    unsigned u[4] = {f.x, f.y, f.z, f.w};
    #pragma unroll
    for (int q = 0; q < 4; ++q) {
        float lo = __uint_as_float(u[q] << 16);
        float hi = __uint_as_float(u[q] & 0xFFFF0000u);
        acc[2*q]   = fmaf(lo, a, acc[2*q]);
        acc[2*q+1] = fmaf(hi, a, acc[2*q+1]);
    }
}

__launch_bounds__(256)
__global__ void k_agg(const unsigned* __restrict__ off, const uint2* __restrict__ es,
                      const float* __restrict__ exs, const ushort_t* __restrict__ ft,
                      float4* __restrict__ out4, float* __restrict__ out_a, int N) {
    int node = (int)((blockIdx.x * (size_t)blockDim.x + threadIdx.x) >> 6);
    if (node >= N) return;
    int lane = threadIdx.x & 63;
    unsigned beg = off[node], end = off[node + 1];

    // ---- pass 1: denominators; contiguous CSR block, 16 edges/step ----
    int h1 = lane >> 4, i16 = lane & 15;
    float s = 0.f;
    for (unsigned j = beg + i16; j < end; j += 16)
        s += exs[j * 4 + h1];
    #pragma unroll
    for (int m = 1; m <= 8; m <<= 1) s += __shfl_xor(s, m, 64);
    float inv_h = (end > beg) ? 1.f / s : 0.f;         // lane's head = h1

    int g  = lane >> 4;              // edge slot 0..3
    int li = lane & 15;              // position in 16-lane group; covers cols li*16..+15
    int h2 = li >> 2;                // head owning those cols
    float inv2 = __shfl(inv_h, h2 * 16, 64);           // denom for pass-2 cols
    float inva = __shfl(inv_h, (lane & 3) * 16, 64);   // denom for out_a writes

    float acc[16];
    #pragma unroll
    for (int q = 0; q < 16; ++q) acc[q] = 0.f;

    // ---- pass 2: four edges per iteration (16-lane group each, 32B/lane) ----
    unsigned j = beg;
    for (; j + 3 < end; j += 4) {
        unsigned jj = j + g;
        uint2 e2 = es[jj];
        float a  = exs[jj * 4 + h2] * inv2;
        float aw = exs[jj * 4 + (lane & 3)];
        const ushort_t* fp = ft + (size_t)e2.y * 256 + li * 16;
        uint4 f0 = *(const uint4*)fp;
        uint4 f1 = *(const uint4*)(fp + 8);
        macc8(acc, f0, a);
        macc8(acc + 8, f1, a);
        if (li < 4) out_a[e2.x * 4 + li] = aw * inva;
    }
    if (j < end) {                   // tail: 1..3 real edges
        unsigned jj = j + g;
        bool act = jj < end;
        unsigned jc = act ? jj : beg;              // beg<end guaranteed here
        uint2 e2 = es[jc];
        float a = act ? exs[jc * 4 + h2] * inv2 : 0.f;
        const ushort_t* fp = ft + (size_t)e2.y * 256 + li * 16;
        uint4 f0 = *(const uint4*)fp;
        uint4 f1 = *(const uint4*)(fp + 8);
        macc8(acc, f0, a);
        macc8(acc + 8, f1, a);
        if (act && li < 4) out_a[e2.x * 4 + li] = exs[jc * 4 + li] * inva;
    }

    // combine the 4 edge-slot groups; lanes 0-15 write the row
    #pragma unroll
    for (int q = 0; q < 16; ++q) {
        acc[q] += __shfl_xor(acc[q], 16, 64);
        acc[q] += __shfl_xor(acc[q], 32, 64);
    }
    if (g == 0) {
        #pragma unroll
        for (int k = 0; k < 4; ++k) {
            float4 o = {acc[k*4], acc[k*4+1], acc[k*4+2], acc[k*4+3]};
            out4[(size_t)node * 64 + li * 4 + k] = o;
        }
    }
}

extern "C" void kernel_launch(void* const* d_in, const int* in_sizes, int n_in,
                              void* d_out, int out_size, void* d_ws, size_t ws_size,
                              hipStream_t stream) {
    const float* feat     = (const float*)d_in[0];
    const int*   e_feat   = (const int*)d_in[1];
    const int*   src      = (const int*)d_in[2];
    const int*   dst      = (const int*)d_in[3];
    const float* W_fc     = (const float*)d_in[4];
    const float* W_e      = (const float*)d_in[5];
    const float* edge_emb = (const float*)d_in[6];
    const float* attn_l   = (const float*)d_in[7];
    const float* attn_r   = (const float*)d_in[8];
    const float* attn_e   = (const float*)d_in[9];

    int N = in_sizes[0] / IN_F;
    int E = in_sizes[1];
    int Mpad   = ((N + BM - 1) / BM) * BM;
    int offpad = (((N + 1) + 4095) >> 12) << 12;   // scan writes full 4096 tiles
    int Epad2  = (E + 1) & ~1;

    float* out_rst = (float*)d_out;
    float* out_a   = out_rst + (size_t)N * C;

    // workspace layout (16B-aligned sections)
    ushort_t* WTbf = (ushort_t*)d_ws;                    // 256*256 bf16
    ushort_t* ftbf = WTbf + 256 * 256;                   // Mpad*256 bf16
    float* el = (float*)(ftbf + (size_t)Mpad * 256);     // N*4
    float* er = el + (size_t)N * H;                      // N*4
    float* ee = er + (size_t)N * H;                      // 64 (32 used)
    unsigned* deg    = (unsigned*)(ee + 64);             // offpad
    unsigned* off    = deg + offpad;                     // offpad
    unsigned* cursor = off + offpad;                     // offpad
    uint2*    es     = (uint2*)(cursor + offpad);        // Epad2
    float4*   exq    = (float4*)(es + Epad2);            // E

    hipMemsetAsync(deg, 0, (size_t)offpad * sizeof(unsigned), stream);

    k_misc   <<<24, 256, 0, stream>>>(W_fc, WTbf, edge_emb, W_e, attn_e, ee);
    k_deg    <<<(E / 4 + 255) / 256, 256, 0, stream>>>(dst, deg, E);
    k_scan   <<<1, 1024, 0, stream>>>(deg, off, cursor, N);
    k_gemm   <<<Mpad / BM, 512, 0, stream>>>(feat, WTbf, attn_l, attn_r, ftbf, el, er, N);
    k_scatlog<<<(E + 255) / 256, 256, 0, stream>>>(dst, src, e_feat, cursor,
                                                   (const float4*)el, (const float4*)er,
                                                   (const float4*)ee, exq, es, E);
    k_agg    <<<((size_t)N * 64 + 255) / 256, 256, 0, stream>>>(off, es, (const float*)exq,
                                                                ftbf, (float4*)out_rst, out_a, N);
}

// Round 6
// 307.980 us; speedup vs baseline: 2.6837x; 1.0059x over previous
//
#include <hip/hip_runtime.h>

#define H 4
#define D 64
#define C 256   // H*D
#define IN_F 256
#define EF 64
#define NEG 0.2f

typedef unsigned short ushort_t;
typedef __attribute__((ext_vector_type(8))) short bf16x8;
typedef __attribute__((ext_vector_type(4))) float f32x4;

struct __align__(32) Rec { float4 ex; unsigned src; unsigned pad[3]; };

__device__ __forceinline__ ushort_t f2bf(float x) {
    unsigned u = __float_as_uint(x);
    unsigned r = u + 0x7FFFu + ((u >> 16) & 1u);   // RNE
    return (ushort_t)(r >> 16);
}

// ---------------- K0: fused {W transpose->bf16} + {etype ee} + {in-degree} ----------------
__global__ void k_front(const float* __restrict__ W, ushort_t* __restrict__ WT,
                        const float* __restrict__ edge_emb, const float* __restrict__ W_e,
                        const float* __restrict__ attn_e, float* __restrict__ ee,
                        const int* __restrict__ dst, unsigned* __restrict__ deg, int E) {
    int b = blockIdx.x;
    if (b < 16) {
        __shared__ float tile[64][65];
        int bi = b >> 2, bj = b & 3;
        int lane = threadIdx.x & 63, wv = threadIdx.x >> 6;
        #pragma unroll
        for (int i = 0; i < 16; ++i) {
            int row = wv * 16 + i;
            tile[row][lane] = W[(size_t)(bi * 64 + row) * 256 + bj * 64 + lane];
        }
        __syncthreads();
        #pragma unroll
        for (int i = 0; i < 16; ++i) {
            int row = wv * 16 + i;
            WT[(size_t)(bj * 64 + row) * 256 + bi * 64 + lane] = f2bf(tile[lane][row]);
        }
    } else if (b < 24) {
        int t = b - 16;                        // etype 0..7
        int c = threadIdx.x;
        float acc = 0.f;
        #pragma unroll 8
        for (int k = 0; k < EF; ++k)
            acc += edge_emb[t * EF + k] * W_e[k * C + c];
        acc *= attn_e[c];
        #pragma unroll
        for (int s = 32; s > 0; s >>= 1) acc += __shfl_down(acc, s, 64);
        if ((threadIdx.x & 63) == 0) ee[t * H + (threadIdx.x >> 6)] = acc;
    } else {
        int i = ((b - 24) * 256 + threadIdx.x) * 4;
        if (i + 3 < E) {
            int4 d = *(const int4*)(dst + i);
            atomicAdd(&deg[d.x], 1u); atomicAdd(&deg[d.y], 1u);
            atomicAdd(&deg[d.z], 1u); atomicAdd(&deg[d.w], 1u);
        } else {
            for (int k = 0; k < 4; ++k)
                if (i + k < E) atomicAdd(&deg[dst[i + k]], 1u);
        }
    }
}

// ---------------- K1: GEMM ft = feat @ W_fc (bf16 MFMA), BN=256, fused el/er ----------------
#define BM 128
#define BK 64
__launch_bounds__(512)
__global__ void k_gemm(const float* __restrict__ feat, const ushort_t* __restrict__ Bbf,
                       const float* __restrict__ attn_l, const float* __restrict__ attn_r,
                       ushort_t* __restrict__ ftbf, float* __restrict__ el, float* __restrict__ er,
                       int N) {
    __shared__ ushort_t As[BM * BK];   // XOR-swizzled chunk (row, kg^(row&7))
    __shared__ ushort_t Bs[C * BK];
    int t = threadIdx.x;
    int l = t & 63, w = t >> 6;
    int wr = w >> 2, wc = w & 3;       // 2x4 waves, 64x64 tiles
    int m0 = blockIdx.x * BM;

    f32x4 zero = {0.f, 0.f, 0.f, 0.f};
    f32x4 acc[4][4];
    #pragma unroll
    for (int i = 0; i < 4; ++i)
        #pragma unroll
        for (int j = 0; j < 4; ++j) acc[i][j] = zero;

    for (int ks = 0; ks < 4; ++ks) {
        #pragma unroll
        for (int i = 0; i < 2; ++i) {
            int c   = t + i * 512;
            int row = c >> 3;
            int kg  = c & 7;
            int kgs = kg ^ (row & 7);
            int gr = m0 + row;
            float4 a0 = {0.f,0.f,0.f,0.f}, a1 = {0.f,0.f,0.f,0.f};
            if (gr < N) {
                const float* ap = feat + (size_t)gr * 256 + ks * BK + kg * 8;
                a0 = *(const float4*)ap;
                a1 = *(const float4*)(ap + 4);
            }
            ushort_t v[8];
            v[0]=f2bf(a0.x); v[1]=f2bf(a0.y); v[2]=f2bf(a0.z); v[3]=f2bf(a0.w);
            v[4]=f2bf(a1.x); v[5]=f2bf(a1.y); v[6]=f2bf(a1.z); v[7]=f2bf(a1.w);
            *(uint4*)(&As[row * BK + kgs * 8]) = *(uint4*)v;
        }
        #pragma unroll
        for (int i = 0; i < 4; ++i) {
            int c   = t + i * 512;
            int row = c >> 3;
            int kg  = c & 7;
            int kgs = kg ^ (row & 7);
            *(uint4*)(&Bs[row * BK + kgs * 8]) =
                *(const uint4*)(Bbf + (size_t)row * 256 + ks * BK + kg * 8);
        }
        __syncthreads();
        #pragma unroll
        for (int k2 = 0; k2 < 2; ++k2) {
            bf16x8 av[4], bv[4];
            int kc = (l >> 4) + k2 * 4;
            #pragma unroll
            for (int i = 0; i < 4; ++i) {
                int ra = wr * 64 + i * 16 + (l & 15);
                av[i] = *(const bf16x8*)(&As[ra * BK + (kc ^ (ra & 7)) * 8]);
                int rb = wc * 64 + i * 16 + (l & 15);
                bv[i] = *(const bf16x8*)(&Bs[rb * BK + (kc ^ (rb & 7)) * 8]);
            }
            #pragma unroll
            for (int i = 0; i < 4; ++i)
                #pragma unroll
                for (int j = 0; j < 4; ++j)
                    acc[i][j] = __builtin_amdgcn_mfma_f32_16x16x32_bf16(av[i], bv[j], acc[i][j], 0, 0, 0);
        }
        __syncthreads();
    }

    int cb = wc * 64;
    int h  = wc;
    float wl[4], wrg[4];
    #pragma unroll
    for (int j = 0; j < 4; ++j) {
        int d = j * 16 + (l & 15);
        wl[j]  = attn_l[h * 64 + d];
        wrg[j] = attn_r[h * 64 + d];
    }
    int rbase = m0 + wr * 64;
    #pragma unroll
    for (int i = 0; i < 4; ++i) {
        #pragma unroll
        for (int r = 0; r < 4; ++r) {
            int m = rbase + i * 16 + (l >> 4) * 4 + r;
            float pl = 0.f, pr = 0.f;
            #pragma unroll
            for (int j = 0; j < 4; ++j) {
                float v = acc[i][j][r];
                ftbf[(size_t)m * 256 + cb + j * 16 + (l & 15)] = f2bf(v);
                pl = fmaf(v, wl[j], pl);
                pr = fmaf(v, wrg[j], pr);
            }
            #pragma unroll
            for (int s2 = 1; s2 <= 8; s2 <<= 1) {
                pl += __shfl_xor(pl, s2, 64);
                pr += __shfl_xor(pr, s2, 64);
            }
            if ((l & 15) == 0 && m < N) { el[m * H + h] = pl; er[m * H + h] = pr; }
        }
    }
}

// ---------------- K2: exclusive scan -> off AND cursor (coalesced) ----------------
__global__ void k_scan(const unsigned* __restrict__ deg, unsigned* __restrict__ off,
                       unsigned* __restrict__ cursor, int n) {
    __shared__ unsigned wsum[16];
    __shared__ unsigned carry_s;
    int t = threadIdx.x;
    int lane = t & 63, wv = t >> 6;
    if (t == 0) carry_s = 0;
    __syncthreads();
    int ns = n + 1;
    int ntile = (ns + 4095) >> 12;
    for (int tile = 0; tile < ntile; ++tile) {
        int i0 = (tile << 12) + t * 4;
        uint4 v;
        if (i0 + 3 < n) {
            v = *(const uint4*)(deg + i0);
        } else {
            v.x = (i0 + 0 < n) ? deg[i0 + 0] : 0u;
            v.y = (i0 + 1 < n) ? deg[i0 + 1] : 0u;
            v.z = (i0 + 2 < n) ? deg[i0 + 2] : 0u;
            v.w = (i0 + 3 < n) ? deg[i0 + 3] : 0u;
        }
        unsigned s = v.x + v.y + v.z + v.w;
        unsigned sc = s;
        #pragma unroll
        for (int d = 1; d < 64; d <<= 1) {
            unsigned u = __shfl_up(sc, d, 64);
            if (lane >= d) sc += u;
        }
        if (lane == 63) wsum[wv] = sc;
        __syncthreads();
        unsigned carry = carry_s;
        unsigned woff = 0;
        #pragma unroll
        for (int k = 0; k < 16; ++k) woff += (k < wv) ? wsum[k] : 0u;
        unsigned ex0 = carry + woff + sc - s;
        uint4 o;
        o.x = ex0; o.y = ex0 + v.x; o.z = o.y + v.y; o.w = o.z + v.z;
        *(uint4*)(off + i0) = o;
        *(uint4*)(cursor + i0) = o;
        __syncthreads();
        if (t == 1023) carry_s = carry + woff + sc;
    }
}

// ---------------- K3: fused scatter+logit: one 32B record per CSR slot ----------------
__global__ void k_scatlog(const int* __restrict__ dst, const int* __restrict__ src,
                          const int* __restrict__ efeat,
                          unsigned* __restrict__ cursor,
                          const float4* __restrict__ el4, const float4* __restrict__ er4,
                          const float4* __restrict__ ee4,
                          Rec* __restrict__ recs, int E) {
    int e = blockIdx.x * 256 + threadIdx.x;
    if (e >= E) return;
    int d = dst[e], s = src[e];
    unsigned q = atomicAdd(&cursor[d], 1u);     // cursor pre-seeded with off
    float4 l = el4[s];
    float4 r = er4[d];
    float4 te = ee4[efeat[e]];
    float4 v;
    v.x = l.x + r.x + te.x; v.y = l.y + r.y + te.y;
    v.z = l.z + r.z + te.z; v.w = l.w + r.w + te.w;
    v.x = v.x > 0.f ? v.x : NEG * v.x;
    v.y = v.y > 0.f ? v.y : NEG * v.y;
    v.z = v.z > 0.f ? v.z : NEG * v.z;
    v.w = v.w > 0.f ? v.w : NEG * v.w;
    v.x = __expf(v.x); v.y = __expf(v.y); v.z = __expf(v.z); v.w = __expf(v.w);
    Rec* rp = &recs[q];
    rp->ex = v;                          // logits O(+-8); softmax shift-invariant
    rp->src = (unsigned)s;
}

// ---------------- K4: wave-per-node softmax denom + 4-edge/iter gather; invs out ----------------
__device__ __forceinline__ void macc8(float* acc, uint4 f, float a) {
    unsigned u[4] = {f.x, f.y, f.z, f.w};
    #pragma unroll
    for (int q = 0; q < 4; ++q) {
        float lo = __uint_as_float(u[q] << 16);
        float hi = __uint_as_float(u[q] & 0xFFFF0000u);
        acc[2*q]   = fmaf(lo, a, acc[2*q]);
        acc[2*q+1] = fmaf(hi, a, acc[2*q+1]);
    }
}

__launch_bounds__(256)
__global__ void k_agg(const unsigned* __restrict__ off, const Rec* __restrict__ recs,
                      const ushort_t* __restrict__ ft, float4* __restrict__ out4,
                      float4* __restrict__ invs, int N) {
    int node = (int)((blockIdx.x * (size_t)blockDim.x + threadIdx.x) >> 6);
    if (node >= N) return;
    int lane = threadIdx.x & 63;
    unsigned beg = off[node], end = off[node + 1];
    const float* rf = (const float*)recs;        // record = 8 floats

    // ---- pass 1: denominators (16 edges/step, one 32B record line per 2 edges) ----
    int h1 = lane >> 4, i16 = lane & 15;
    float s = 0.f;
    for (unsigned j = beg + i16; j < end; j += 16)
        s += rf[(size_t)j * 8 + h1];
    #pragma unroll
    for (int m = 1; m <= 8; m <<= 1) s += __shfl_xor(s, m, 64);
    float inv_h = (end > beg) ? 1.f / s : 0.f;   // lane's head = h1

    float i0 = __shfl(inv_h, 0, 64),  i1 = __shfl(inv_h, 16, 64),
          i2 = __shfl(inv_h, 32, 64), i3 = __shfl(inv_h, 48, 64);
    if (lane == 0) invs[node] = make_float4(i0, i1, i2, i3);

    int g  = lane >> 4;              // edge slot 0..3
    int li = lane & 15;              // covers cols li*16..+15
    int h2 = li >> 2;                // head owning those cols
    float inv2 = (h2 == 0) ? i0 : (h2 == 1) ? i1 : (h2 == 2) ? i2 : i3;

    float acc[16];
    #pragma unroll
    for (int q = 0; q < 16; ++q) acc[q] = 0.f;

    // ---- pass 2: four edges per iteration (16-lane group each, 32B/lane gather) ----
    unsigned j = beg;
    for (; j + 3 < end; j += 4) {
        unsigned jj = j + g;
        float a = rf[(size_t)jj * 8 + h2] * inv2;
        unsigned sn = ((const unsigned*)recs)[(size_t)jj * 8 + 4];
        const ushort_t* fp = ft + (size_t)sn * 256 + li * 16;
        uint4 f0 = *(const uint4*)fp;
        uint4 f1 = *(const uint4*)(fp + 8);
        macc8(acc, f0, a);
        macc8(acc + 8, f1, a);
    }
    if (j < end) {                   // tail: 1..3 real edges
        unsigned jj = j + g;
        bool act = jj < end;
        unsigned jc = act ? jj : beg;            // beg<end guaranteed here
        float a = act ? rf[(size_t)jc * 8 + h2] * inv2 : 0.f;
        unsigned sn = ((const unsigned*)recs)[(size_t)jc * 8 + 4];
        const ushort_t* fp = ft + (size_t)sn * 256 + li * 16;
        uint4 f0 = *(const uint4*)fp;
        uint4 f1 = *(const uint4*)(fp + 8);
        macc8(acc, f0, a);
        macc8(acc + 8, f1, a);
    }

    // combine the 4 edge-slot groups; lanes 0-15 write the row
    #pragma unroll
    for (int q = 0; q < 16; ++q) {
        acc[q] += __shfl_xor(acc[q], 16, 64);
        acc[q] += __shfl_xor(acc[q], 32, 64);
    }
    if (g == 0) {
        #pragma unroll
        for (int k = 0; k < 4; ++k) {
            float4 o = {acc[k*4], acc[k*4+1], acc[k*4+2], acc[k*4+3]};
            out4[(size_t)node * 64 + li * 4 + k] = o;
        }
    }
}

// ---------------- K5: edge-order alpha write (coalesced; recompute logit) ----------------
__global__ void k_alpha(const int* __restrict__ dst, const int* __restrict__ src,
                        const int* __restrict__ efeat,
                        const float4* __restrict__ el4, const float4* __restrict__ er4,
                        const float4* __restrict__ ee4, const float4* __restrict__ invs,
                        float4* __restrict__ out_a4, int E) {
    int e = blockIdx.x * 256 + threadIdx.x;
    if (e >= E) return;
    int d = dst[e], s = src[e];
    float4 l = el4[s];
    float4 r = er4[d];
    float4 te = ee4[efeat[e]];
    float4 v;
    v.x = l.x + r.x + te.x; v.y = l.y + r.y + te.y;
    v.z = l.z + r.z + te.z; v.w = l.w + r.w + te.w;
    v.x = v.x > 0.f ? v.x : NEG * v.x;
    v.y = v.y > 0.f ? v.y : NEG * v.y;
    v.z = v.z > 0.f ? v.z : NEG * v.z;
    v.w = v.w > 0.f ? v.w : NEG * v.w;
    v.x = __expf(v.x); v.y = __expf(v.y); v.z = __expf(v.z); v.w = __expf(v.w);
    float4 iv = invs[d];
    v.x *= iv.x; v.y *= iv.y; v.z *= iv.z; v.w *= iv.w;
    out_a4[e] = v;
}

extern "C" void kernel_launch(void* const* d_in, const int* in_sizes, int n_in,
                              void* d_out, int out_size, void* d_ws, size_t ws_size,
                              hipStream_t stream) {
    const float* feat     = (const float*)d_in[0];
    const int*   e_feat   = (const int*)d_in[1];
    const int*   src      = (const int*)d_in[2];
    const int*   dst      = (const int*)d_in[3];
    const float* W_fc     = (const float*)d_in[4];
    const float* W_e      = (const float*)d_in[5];
    const float* edge_emb = (const float*)d_in[6];
    const float* attn_l   = (const float*)d_in[7];
    const float* attn_r   = (const float*)d_in[8];
    const float* attn_e   = (const float*)d_in[9];

    int N = in_sizes[0] / IN_F;
    int E = in_sizes[1];
    int Mpad   = ((N + BM - 1) / BM) * BM;
    int offpad = (((N + 1) + 4095) >> 12) << 12;   // scan writes full 4096 tiles

    float* out_rst = (float*)d_out;
    float* out_a   = out_rst + (size_t)N * C;

    // workspace layout (32B-aligned sections)
    ushort_t* WTbf = (ushort_t*)d_ws;                    // 256*256 bf16
    ushort_t* ftbf = WTbf + 256 * 256;                   // Mpad*256 bf16
    float* el = (float*)(ftbf + (size_t)Mpad * 256);     // N*4
    float* er = el + (size_t)N * H;                      // N*4
    float* ee = er + (size_t)N * H;                      // 64 (32 used)
    float* invs = ee + 64;                               // N*4
    unsigned* deg    = (unsigned*)(invs + (size_t)N * H);// offpad
    unsigned* off    = deg + offpad;                     // offpad
    unsigned* cursor = off + offpad;                     // offpad
    Rec* recs        = (Rec*)(cursor + offpad);          // E * 32B

    hipMemsetAsync(deg, 0, (size_t)offpad * sizeof(unsigned), stream);

    int degblocks = (E / 4 + 255) / 256;
    k_front  <<<24 + degblocks, 256, 0, stream>>>(W_fc, WTbf, edge_emb, W_e, attn_e, ee,
                                                  dst, deg, E);
    k_scan   <<<1, 1024, 0, stream>>>(deg, off, cursor, N);
    k_gemm   <<<Mpad / BM, 512, 0, stream>>>(feat, WTbf, attn_l, attn_r, ftbf, el, er, N);
    k_scatlog<<<(E + 255) / 256, 256, 0, stream>>>(dst, src, e_feat, cursor,
                                                   (const float4*)el, (const float4*)er,
                                                   (const float4*)ee, recs, E);
    k_agg    <<<((size_t)N * 64 + 255) / 256, 256, 0, stream>>>(off, recs, ftbf,
                                                                (float4*)out_rst,
                                                                (float4*)invs, N);
    k_alpha  <<<(E + 255) / 256, 256, 0, stream>>>(dst, src, e_feat,
                                                   (const float4*)el, (const float4*)er,
                                                   (const float4*)ee, (const float4*)invs,
                                                   (float4*)out_a, E);
}